// Round 10
// baseline (240.079 us; speedup 1.0000x reference)
//
#include <hip/hip_runtime.h>

#define HW_ 65536
#define W_ 1024
#define H_ 64
#define B_ 2
#define C_ 68
#define NPIX 131072
#define EPS 1e-5f
#define SCOLS 258            // stats kernels: 256-pixel tiles
#define FSC 130              // k_fused: 128-pixel tiles

typedef __attribute__((ext_vector_type(8))) short short8;
typedef __attribute__((ext_vector_type(4))) float floatx4;

__device__ __forceinline__ unsigned short f2bf(float f) {
  unsigned u = __float_as_uint(f);
  u += 0x7fffu + ((u >> 16) & 1u);
  return (unsigned short)(u >> 16);
}
__device__ __forceinline__ unsigned pack2(float a, float b) {
  return (unsigned)f2bf(a) | ((unsigned)f2bf(b) << 16);
}
__device__ __forceinline__ float wred(float v) {
  v += __shfl_xor(v, 1);  v += __shfl_xor(v, 2);  v += __shfl_xor(v, 4);
  v += __shfl_xor(v, 8);  v += __shfl_xor(v, 16); v += __shfl_xor(v, 32);
  return v;
}
__device__ __forceinline__ int swz_tile(int bid) {
  // XCD-contiguous (512 tiles): XCD j owns tiles [j*64, j*64+64)
  return (bid & 7) * 64 + (bid >> 3);
}

// Stage 3 rows x (SC cols) of x ch0-3 and mask into LDS. OOB -> 0.
template <int NT, int SC>
__device__ __forceinline__ void stage_rows(const float* xb, const float* mb,
                                           int h, int w0, float* stg, int tid) {
  const int tot = 15 * SC;
#pragma unroll 1
  for (int i = tid; i < tot; i += NT) {
    int seg = i / SC, col = i - seg * SC;
    int arr = seg / 3, row = seg - arr * 3;
    int wg = w0 - 1 + col, hg = h + row - 1;
    bool ok = ((unsigned)wg < (unsigned)W_) && ((unsigned)hg < (unsigned)H_);
    float v = 0.f;
    if (ok) v = (arr < 4) ? xb[(size_t)arr * HW_ + (hg << 10) + wg]
                          : mb[(hg << 10) + wg];
    stg[i] = v;
  }
}

#define XSTG(ch, row, col) stg[((ch) * 3 + (row)) * SCOLS + (col)]
#define MSTG(row, col)     stg[(12 + (row)) * SCOLS + (col)]
#define XF(ch, row, col)   stg[((ch) * 3 + (row)) * FSC + (col)]
#define MF(row, col)       stg[(12 + (row)) * FSC + (col)]

// ---- K1: stats1 via moment matrix. ws[0..3]=S=sum(pn), ws[4..13]=M=sum(pn pn^T)
// packed (00,01,02,03,11,12,13,22,23,33), ws[14]=masked count, ws[15]=center count.
__global__ __launch_bounds__(256, 4) void k_stats1(
    const float* __restrict__ x, const float* __restrict__ mask,
    float* __restrict__ ws) {
  __shared__ float stg[15 * SCOLS];
  __shared__ float red[4][16];
  int tile = swz_tile(blockIdx.x);
  int p0 = tile * 256;
  int b = p0 >> 16, s0 = p0 & (HW_ - 1);
  int h = s0 >> 10, w0 = s0 & (W_ - 1);
  const float* xb = x + (size_t)b * C_ * HW_;
  const float* mb = mask + (size_t)b * HW_;
  stage_rows<256, SCOLS>(xb, mb, h, w0, stg, threadIdx.x);
  __syncthreads();

  int pix = threadIdx.x;
  float xc0 = XSTG(0, 1, 1 + pix), xc1 = XSTG(1, 1, 1 + pix);
  float xc2 = XSTG(2, 1, 1 + pix), xc3 = XSTG(3, 1, 1 + pix);

  float a[16];
#pragma unroll
  for (int i = 0; i < 16; i++) a[i] = 0.f;
  a[15] = (MSTG(1, 1 + pix) > 0.f) ? 1.f : 0.f;

#pragma unroll
  for (int k = 0; k < 9; k++) {
    int row = k / 3, col = 1 + pix + (k % 3 - 1);
    float mval = MSTG(row, col);
    if (mval > 0.f) {
      float pn0 = XSTG(0, row, col) - xc0;
      float pn1 = XSTG(1, row, col) - xc1;
      float pn2 = XSTG(2, row, col) - xc2;
      float pn3 = XSTG(3, row, col) - xc3;
      a[14] += 1.f;
      a[0] += pn0; a[1] += pn1; a[2] += pn2; a[3] += pn3;
      a[4] += pn0 * pn0; a[5] += pn0 * pn1; a[6] += pn0 * pn2; a[7] += pn0 * pn3;
      a[8] += pn1 * pn1; a[9] += pn1 * pn2; a[10] += pn1 * pn3;
      a[11] += pn2 * pn2; a[12] += pn2 * pn3; a[13] += pn3 * pn3;
    }
  }
  int lane = threadIdx.x & 63, wave = threadIdx.x >> 6;
#pragma unroll
  for (int i = 0; i < 16; i++) {
    float rv = wred(a[i]);
    if (lane == 0) red[wave][i] = rv;
  }
  __syncthreads();
  if (threadIdx.x < 16)
    atomicAdd(&ws[threadIdx.x],
              red[0][threadIdx.x] + red[1][threadIdx.x] + red[2][threadIdx.x] + red[3][threadIdx.x]);
}

// ---- K2: stats2, 2 threads/pixel (grid 1024); gbn1 scale from S/M ----
__global__ __launch_bounds__(256, 4) void k_stats2(
    const float* __restrict__ x, const float* __restrict__ mask,
    const float* __restrict__ g1, const float* __restrict__ gbn1_g,
    const float* __restrict__ gbn1_b, const float* __restrict__ g2,
    float* __restrict__ ws) {
  __shared__ float stg[15 * SCOLS];
  __shared__ float red[4][16];
  __shared__ float sc[8], sh[8];
  if (threadIdx.x < 8) {
    int o = threadIdx.x;
    float a0 = g1[o * 4], a1 = g1[o * 4 + 1], a2 = g1[o * 4 + 2], a3 = g1[o * 4 + 3];
    float n = fmaxf(ws[14], 1.f);
    float mean = (a0 * ws[0] + a1 * ws[1] + a2 * ws[2] + a3 * ws[3]) / n;
    float q = a0 * a0 * ws[4] + a1 * a1 * ws[8] + a2 * a2 * ws[11] + a3 * a3 * ws[13]
            + 2.f * (a0 * a1 * ws[5] + a0 * a2 * ws[6] + a0 * a3 * ws[7]
                   + a1 * a2 * ws[9] + a1 * a3 * ws[10] + a2 * a3 * ws[12]);
    float var = q / n - mean * mean;
    float s_ = gbn1_g[o] * rsqrtf(var + EPS);
    sc[o] = s_; sh[o] = gbn1_b[o] - mean * s_;
  }
  int half = blockIdx.x >> 9;
  int tile = swz_tile(blockIdx.x & 511);
  int p0 = tile * 256;
  int b = p0 >> 16, s0 = p0 & (HW_ - 1);
  int h = s0 >> 10, w0 = s0 & (W_ - 1);
  const float* xb = x + (size_t)b * C_ * HW_;
  const float* mb = mask + (size_t)b * HW_;
  stage_rows<256, SCOLS>(xb, mb, h, w0, stg, threadIdx.x);
  __syncthreads();

  int pix = threadIdx.x;
  float xc0 = XSTG(0, 1, 1 + pix), xc1 = XSTG(1, 1, 1 + pix);
  float xc2 = XSTG(2, 1, 1 + pix), xc3 = XSTG(3, 1, 1 + pix);

  float acc2[16];
#pragma unroll
  for (int i = 0; i < 16; i++) acc2[i] = 0.f;

  int kb = half ? 5 : 0, ke = half ? 9 : 5;
#pragma unroll
  for (int k = 0; k < 9; k++) {
    if (k < kb || k >= ke) continue;
    int row = k / 3, col = 1 + pix + (k % 3 - 1);
    float mval = MSTG(row, col);
    if (mval > 0.f) {
      float pn0 = XSTG(0, row, col) - xc0;
      float pn1 = XSTG(1, row, col) - xc1;
      float pn2 = XSTG(2, row, col) - xc2;
      float pn3 = XSTG(3, row, col) - xc3;
      float gb[8];
#pragma unroll
      for (int o = 0; o < 8; o++) {
        float tg = pn0 * g1[o * 4] + pn1 * g1[o * 4 + 1] + pn2 * g1[o * 4 + 2] + pn3 * g1[o * 4 + 3];
        gb[o] = fmaxf(sc[o] * tg + sh[o], 0.f);
      }
#pragma unroll
      for (int j = 0; j < 8; j++) {
        float t2 = 0.f;
#pragma unroll
        for (int o = 0; o < 8; o++) t2 += gb[o] * g2[j * 8 + o];
        acc2[j] += t2; acc2[8 + j] += t2 * t2;
      }
    }
  }
  int lane = threadIdx.x & 63, wave = threadIdx.x >> 6;
#pragma unroll
  for (int i = 0; i < 16; i++) {
    float rv = wred(acc2[i]);
    if (lane == 0) red[wave][i] = rv;
  }
  __syncthreads();
  if (threadIdx.x < 16)
    atomicAdd(&ws[40 + threadIdx.x],
              red[0][threadIdx.x] + red[1][threadIdx.x] + red[2][threadIdx.x] + red[3][threadIdx.x]);
}

// --------- K3: fused kernel, 512 thr / 128 pixels (4 thr/pixel) -------------
// quarters own neighbors {0,1,2},{3,4},{5,6},{7,8}; fagg 16 channels each.
// LDS ~39.6KB -> 3-4 blocks/CU (was 79.4KB -> 2).
__global__ __launch_bounds__(512, 6) void k_fused(
    const float* __restrict__ x, const float* __restrict__ mask,
    const float* __restrict__ w1, const float* __restrict__ bn1_g,
    const float* __restrict__ bn1_b, const float* __restrict__ w2,
    const float* __restrict__ b2, const float* __restrict__ g1,
    const float* __restrict__ gbn1_g, const float* __restrict__ gbn1_b,
    const float* __restrict__ g2, const float* __restrict__ gbn2_g,
    const float* __restrict__ gbn2_b, const float* __restrict__ w_agg,
    const float* __restrict__ ws, float* __restrict__ out_pre,
    float* __restrict__ wsum) {
  __shared__ uint4 vecA[17][128];   // 34.8 KB : staging overlay, then bf16 chunks
  __shared__ float evb[9][128];     // 4.5 KB  : softmax logit exchange
  __shared__ float sA[8], hA[8], sG1[8], hG1[8], sG2[8], hG2[8];
  float* stg = (float*)&vecA[0][0]; // 7.8 KB < chunks-8+ offset (16 KB): phase-3 safe

  if (threadIdx.x < 16) {
    int o = threadIdx.x & 7;
    const float* wv = (threadIdx.x < 8) ? w1 : g1;
    float a0 = wv[o * 4], a1 = wv[o * 4 + 1], a2 = wv[o * 4 + 2], a3 = wv[o * 4 + 3];
    float n = fmaxf(ws[14], 1.f);
    float mean = (a0 * ws[0] + a1 * ws[1] + a2 * ws[2] + a3 * ws[3]) / n;
    float q = a0 * a0 * ws[4] + a1 * a1 * ws[8] + a2 * a2 * ws[11] + a3 * a3 * ws[13]
            + 2.f * (a0 * a1 * ws[5] + a0 * a2 * ws[6] + a0 * a3 * ws[7]
                   + a1 * a2 * ws[9] + a1 * a3 * ws[10] + a2 * a3 * ws[12]);
    float var = q / n - mean * mean;
    float gma = (threadIdx.x < 8) ? bn1_g[o] : gbn1_g[o];
    float bta = (threadIdx.x < 8) ? bn1_b[o] : gbn1_b[o];
    float s_ = gma * rsqrtf(var + EPS);
    float sft = bta - mean * s_;
    if (threadIdx.x < 8) { sA[o] = s_;  hA[o] = sft; }
    else                 { sG1[o] = s_; hG1[o] = sft; }
  } else if (threadIdx.x < 24) {
    int o = threadIdx.x & 7;
    float n = fmaxf(ws[14], 1.f);
    float mean = ws[40 + o] / n, var = ws[48 + o] / n - mean * mean;
    float s_ = gbn2_g[o] * rsqrtf(var + EPS);
    sG2[o] = s_; hG2[o] = gbn2_b[o] - mean * s_;
  }

  int tid = threadIdx.x;
  int quarter = tid >> 7;   // wave-uniform (2 waves per quarter)
  int pix = tid & 127;
  int tile = (blockIdx.x & 7) * 128 + (blockIdx.x >> 3);  // XCD-contiguous, 1024 tiles
  int p0 = tile * 128;
  int b = p0 >> 16, s0 = p0 & (HW_ - 1);
  int h = s0 >> 10, w0 = s0 & (W_ - 1);
  const float* xb = x + (size_t)b * C_ * HW_;
  const float* mb = mask + (size_t)b * HW_;
  stage_rows<512, FSC>(xb, mb, h, w0, stg, tid);
  __syncthreads();

  float xc0 = XF(0, 1, 1 + pix), xc1 = XF(1, 1, 1 + pix);
  float xc2 = XF(2, 1, 1 + pix), xc3 = XF(3, 1, 1 + pix);
  float b2v = b2[0];

  // quarter k-ranges: q0 [0,3), q1 [3,5), q2 [5,7), q3 [7,9)
  int kb = (quarter == 0) ? 0 : (2 * quarter + 1);
  int ke = 2 * quarter + 3;

  // ---- phase 1: softmax logits for my neighbors; cache pn in registers ----
  float pnc[3][4];
  unsigned mbits = 0u;
#pragma unroll
  for (int k = 0; k < 9; k++) {
    if (k < kb || k >= ke) continue;
    int j = k - kb;
    int row = k / 3, col = 1 + pix + (k % 3 - 1);
    float mval = MF(row, col);
    float wp = 0.f;
    pnc[j][0] = 0.f; pnc[j][1] = 0.f; pnc[j][2] = 0.f; pnc[j][3] = 0.f;
    if (mval > 0.f) {
      mbits |= (1u << k);
      pnc[j][0] = XF(0, row, col) - xc0;
      pnc[j][1] = XF(1, row, col) - xc1;
      pnc[j][2] = XF(2, row, col) - xc2;
      pnc[j][3] = XF(3, row, col) - xc3;
      float accw = 0.f;
#pragma unroll
      for (int o = 0; o < 8; o++) {
        float ta = pnc[j][0] * w1[o * 4] + pnc[j][1] * w1[o * 4 + 1] +
                   pnc[j][2] * w1[o * 4 + 2] + pnc[j][3] * w1[o * 4 + 3];
        accw += fmaxf(sA[o] * ta + hA[o], 0.f) * w2[o];
      }
      wp = accw + b2v;
    }
    evb[k][pix] = wp;
  }
  __syncthreads();   // evb ready; staging reads done before phase-4 overwrite

  // ---- phase 2: all quarters compute identical softmax weights ----
  float ev[9];
  float mx = -1e30f;
#pragma unroll
  for (int k = 0; k < 9; k++) { ev[k] = evb[k][pix]; mx = fmaxf(mx, ev[k]); }
  float den = 0.f;
#pragma unroll
  for (int k = 0; k < 9; k++) { ev[k] = __expf(ev[k] - mx); den += ev[k]; }
  float inv = 1.f / den;

  // ---- phase 3: g-vec for my neighbors (register pn, zero loads) ----
#pragma unroll
  for (int k = 0; k < 9; k++) {
    if (k < kb || k >= ke) continue;
    int j = k - kb;
    uint4 pk; pk.x = pk.y = pk.z = pk.w = 0u;
    if ((mbits >> k) & 1u) {
      float wt = ev[k] * inv;
      float gb[8];
#pragma unroll
      for (int o = 0; o < 8; o++) {
        float tg = pnc[j][0] * g1[o * 4] + pnc[j][1] * g1[o * 4 + 1] +
                   pnc[j][2] * g1[o * 4 + 2] + pnc[j][3] * g1[o * 4 + 3];
        gb[o] = fmaxf(sG1[o] * tg + hG1[o], 0.f);
      }
      float gv[8];
#pragma unroll
      for (int j2 = 0; j2 < 8; j2++) {
        float t2 = 0.f;
#pragma unroll
        for (int o = 0; o < 8; o++) t2 += gb[o] * g2[j2 * 8 + o];
        float gg = fmaxf(sG2[j2] * t2 + hG2[j2], 0.f);
        gv[j2] = wt * gg;
      }
      pk.x = pack2(gv[0], gv[1]); pk.y = pack2(gv[2], gv[3]);
      pk.z = pack2(gv[4], gv[5]); pk.w = pack2(gv[6], gv[7]);
    }
    vecA[8 + k][pix] = pk;
  }

  // ---- phase 4: fagg over my 16 channels, all 9 neighbors (coalesced) ----
  float facc[16];
#pragma unroll
  for (int c = 0; c < 16; c++) facc[c] = 0.f;
#pragma unroll
  for (int k = 0; k < 9; k++) {
    int di = k / 3 - 1, dj = k % 3 - 1;
    int hh = h + di, ww = w0 + pix + dj;
    bool inb = ((unsigned)hh < (unsigned)H_) && ((unsigned)ww < (unsigned)W_);
    if (inb) {
      int ns = (hh << 10) + ww;
      float wt = ev[k] * inv;
      const float* xf = xb + (size_t)(4 + quarter * 16) * HW_ + ns;
#pragma unroll
      for (int c = 0; c < 16; c++) facc[c] += wt * xf[(size_t)c * HW_];
    }
  }
#pragma unroll
  for (int c0 = 0; c0 < 16; c0 += 8) {
    uint4 pk;
    pk.x = pack2(facc[c0], facc[c0 + 1]);     pk.y = pack2(facc[c0 + 2], facc[c0 + 3]);
    pk.z = pack2(facc[c0 + 4], facc[c0 + 5]); pk.w = pack2(facc[c0 + 6], facc[c0 + 7]);
    vecA[quarter * 2 + (c0 >> 3)][pix] = pk;
  }
  __syncthreads();

  // ---- GEMM: D[pixel 128][chan 64] = vecA @ w_agg^T, 8 waves (4 m-pair x 2 n)
  int lane = tid & 63, wave = tid >> 6;
  int q = lane >> 4, r = lane & 15;
  int wr = wave >> 1, wc = wave & 1;

  short8 Bf[2][5];
#pragma unroll
  for (int nt = 0; nt < 2; nt++) {
    int n = wc * 32 + nt * 16 + r;
#pragma unroll
    for (int ks = 0; ks < 5; ks++) {
      int k0 = ks * 32 + q * 8;
      uint4 pk; pk.x = pk.y = pk.z = pk.w = 0u;
      if (k0 < 136) {
        float4 f0 = *reinterpret_cast<const float4*>(w_agg + n * 136 + k0);
        float4 f1 = *reinterpret_cast<const float4*>(w_agg + n * 136 + k0 + 4);
        pk.x = pack2(f0.x, f0.y); pk.y = pack2(f0.z, f0.w);
        pk.z = pack2(f1.x, f1.y); pk.w = pack2(f1.z, f1.w);
      }
      Bf[nt][ks] = *reinterpret_cast<short8*>(&pk);
    }
  }

  floatx4 acc[2][2];
#pragma unroll
  for (int m = 0; m < 2; m++)
#pragma unroll
    for (int nt = 0; nt < 2; nt++) acc[m][nt] = (floatx4){0.f, 0.f, 0.f, 0.f};

#pragma unroll
  for (int m = 0; m < 2; m++) {
    int pixm = (wr * 2 + m) * 16 + r;
    short8 Af[5];
#pragma unroll
    for (int ks = 0; ks < 5; ks++) {
      int chunk = ks * 4 + q;
      if (chunk < 17)
        Af[ks] = *reinterpret_cast<const short8*>(&vecA[chunk][pixm]);
      else
        Af[ks] = (short8){0, 0, 0, 0, 0, 0, 0, 0};
    }
#pragma unroll
    for (int nt = 0; nt < 2; nt++)
#pragma unroll
      for (int ks = 0; ks < 5; ks++)
        acc[m][nt] = __builtin_amdgcn_mfma_f32_16x16x32_bf16(Af[ks], Bf[nt][ks], acc[m][nt], 0, 0, 0);
  }

  // ---- store (f32, full-line coalesced) + masked abn partial sums ----
  float aS[2] = {0.f, 0.f}, aQ[2] = {0.f, 0.f};
#pragma unroll
  for (int m = 0; m < 2; m++) {
    int mt = wr * 2 + m;
    int srow = s0 + mt * 16 + q * 4;
    float4 mv = *reinterpret_cast<const float4*>(mb + srow);
    float m0 = (mv.x > 0.f) ? 1.f : 0.f, m1 = (mv.y > 0.f) ? 1.f : 0.f;
    float m2 = (mv.z > 0.f) ? 1.f : 0.f, m3 = (mv.w > 0.f) ? 1.f : 0.f;
#pragma unroll
    for (int nt = 0; nt < 2; nt++) {
      int ch = wc * 32 + nt * 16 + r;
      float4 ov;
      ov.x = acc[m][nt][0]; ov.y = acc[m][nt][1];
      ov.z = acc[m][nt][2]; ov.w = acc[m][nt][3];
      aS[nt] += ov.x * m0 + ov.y * m1 + ov.z * m2 + ov.w * m3;
      aQ[nt] += ov.x * ov.x * m0 + ov.y * ov.y * m1 + ov.z * ov.z * m2 + ov.w * ov.w * m3;
      *reinterpret_cast<float4*>(out_pre + ((size_t)(b * 64 + ch)) * HW_ + srow) = ov;
    }
  }

  __syncthreads();  // all vecA ds_reads done; reuse LDS for reduction
  float* rS = (float*)&vecA[0][0];   // [8 waves][2 nt][16 r]
  float* rQ = rS + 256;
#pragma unroll
  for (int nt = 0; nt < 2; nt++) {
    float v1 = aS[nt], v2 = aQ[nt];
    v1 += __shfl_xor(v1, 16); v1 += __shfl_xor(v1, 32);
    v2 += __shfl_xor(v2, 16); v2 += __shfl_xor(v2, 32);
    if (lane < 16) { rS[wave * 32 + nt * 16 + lane] = v1; rQ[wave * 32 + nt * 16 + lane] = v2; }
  }
  __syncthreads();
  if (tid < 64) {
    int c = tid;
    int wc_ = c >> 5, nt_ = (c >> 4) & 1, r_ = c & 15;
    float s1 = 0.f, s2 = 0.f;
#pragma unroll
    for (int wr_ = 0; wr_ < 4; wr_++) {
      int idx = (wr_ * 2 + wc_) * 32 + nt_ * 16 + r_;
      s1 += rS[idx]; s2 += rQ[idx];
    }
    atomicAdd(&wsum[64 + c], s1);
    atomicAdd(&wsum[128 + c], s2);
  }
}

// ---------------- K4: abn apply + relu + center-mask zero (f32 in) ----------
__global__ __launch_bounds__(256) void k_final(
    const float* __restrict__ out_pre, const float* __restrict__ mask,
    const float* __restrict__ abn_g, const float* __restrict__ abn_b,
    const float* __restrict__ ws, float* __restrict__ out) {
  __shared__ float sc[64], sh[64];
  if (threadIdx.x < 64) {
    int c = threadIdx.x;
    float n0 = fmaxf(ws[15], 1.f);
    float mean = ws[64 + c] / n0;
    float var = ws[128 + c] / n0 - mean * mean;
    float s_ = abn_g[c] * rsqrtf(var + EPS);
    sc[c] = s_; sh[c] = abn_b[c] - mean * s_;
  }
  __syncthreads();
  int i4 = (blockIdx.x * 256 + threadIdx.x) * 4;
  if (i4 >= B_ * 64 * HW_) return;
  int c = (i4 >> 16) & 63;
  int b = i4 >> 22;
  int s = i4 & (HW_ - 1);
  float4 v = *reinterpret_cast<const float4*>(out_pre + i4);
  float4 m = *reinterpret_cast<const float4*>(mask + (size_t)b * HW_ + s);
  float4 o;
  o.x = (m.x > 0.f) ? fmaxf(v.x * sc[c] + sh[c], 0.f) : 0.f;
  o.y = (m.y > 0.f) ? fmaxf(v.y * sc[c] + sh[c], 0.f) : 0.f;
  o.z = (m.z > 0.f) ? fmaxf(v.z * sc[c] + sh[c], 0.f) : 0.f;
  o.w = (m.w > 0.f) ? fmaxf(v.w * sc[c] + sh[c], 0.f) : 0.f;
  *reinterpret_cast<float4*>(out + i4) = o;
}

extern "C" void kernel_launch(void* const* d_in, const int* in_sizes, int n_in,
                              void* d_out, int out_size, void* d_ws, size_t ws_size,
                              hipStream_t stream) {
  const float* x      = (const float*)d_in[0];
  const float* mask   = (const float*)d_in[1];
  const float* w1     = (const float*)d_in[2];
  const float* bn1_g  = (const float*)d_in[3];
  const float* bn1_b  = (const float*)d_in[4];
  const float* w2     = (const float*)d_in[5];
  const float* b2     = (const float*)d_in[6];
  const float* g1     = (const float*)d_in[7];
  const float* gbn1_g = (const float*)d_in[8];
  const float* gbn1_b = (const float*)d_in[9];
  const float* g2     = (const float*)d_in[10];
  const float* gbn2_g = (const float*)d_in[11];
  const float* gbn2_b = (const float*)d_in[12];
  const float* w_agg  = (const float*)d_in[13];
  const float* abn_g  = (const float*)d_in[14];
  const float* abn_b  = (const float*)d_in[15];
  float* out = (float*)d_out;

  size_t need = 1024 + (size_t)NPIX * 64 * 4;
  if (ws_size < need) return;

  float* wsf = (float*)d_ws;
  float* out_pre = (float*)((char*)d_ws + 1024);

  hipMemsetAsync(d_ws, 0, 1024, stream);
  k_stats1<<<512, 256, 0, stream>>>(x, mask, wsf);
  k_stats2<<<1024, 256, 0, stream>>>(x, mask, g1, gbn1_g, gbn1_b, g2, wsf);
  k_fused<<<1024, 512, 0, stream>>>(x, mask, w1, bn1_g, bn1_b, w2, b2, g1,
                                    gbn1_g, gbn1_b, g2, gbn2_g, gbn2_b, w_agg,
                                    wsf, out_pre, wsf);
  k_final<<<8192, 256, 0, stream>>>(out_pre, mask, abn_g, abn_b, wsf, out);
}

// Round 11
// 204.673 us; speedup vs baseline: 1.1730x; 1.1730x over previous
//
#include <hip/hip_runtime.h>

#define HW_ 65536
#define W_ 1024
#define H_ 64
#define B_ 2
#define C_ 68
#define NPIX 131072
#define EPS 1e-5f
#define SCOLS 258            // stats kernels: 256-pixel tiles
#define FSC 130              // k_fused: 128-pixel tiles

typedef __attribute__((ext_vector_type(8))) short short8;
typedef __attribute__((ext_vector_type(4))) float floatx4;

__device__ __forceinline__ unsigned short f2bf(float f) {
  unsigned u = __float_as_uint(f);
  u += 0x7fffu + ((u >> 16) & 1u);
  return (unsigned short)(u >> 16);
}
__device__ __forceinline__ unsigned pack2(float a, float b) {
  return (unsigned)f2bf(a) | ((unsigned)f2bf(b) << 16);
}
__device__ __forceinline__ float wred(float v) {
  v += __shfl_xor(v, 1);  v += __shfl_xor(v, 2);  v += __shfl_xor(v, 4);
  v += __shfl_xor(v, 8);  v += __shfl_xor(v, 16); v += __shfl_xor(v, 32);
  return v;
}
__device__ __forceinline__ int swz_tile(int bid) {
  // XCD-contiguous (512 tiles): XCD j owns tiles [j*64, j*64+64)
  return (bid & 7) * 64 + (bid >> 3);
}

// Stage 3 rows x (SC cols) of x ch0-3 and mask into LDS. OOB -> 0.
template <int NT, int SC>
__device__ __forceinline__ void stage_rows(const float* xb, const float* mb,
                                           int h, int w0, float* stg, int tid) {
  const int tot = 15 * SC;
#pragma unroll 1
  for (int i = tid; i < tot; i += NT) {
    int seg = i / SC, col = i - seg * SC;
    int arr = seg / 3, row = seg - arr * 3;
    int wg = w0 - 1 + col, hg = h + row - 1;
    bool ok = ((unsigned)wg < (unsigned)W_) && ((unsigned)hg < (unsigned)H_);
    float v = 0.f;
    if (ok) v = (arr < 4) ? xb[(size_t)arr * HW_ + (hg << 10) + wg]
                          : mb[(hg << 10) + wg];
    stg[i] = v;
  }
}

#define XSTG(ch, row, col) stg[((ch) * 3 + (row)) * SCOLS + (col)]
#define MSTG(row, col)     stg[(12 + (row)) * SCOLS + (col)]
#define XF(ch, row, col)   stg[((ch) * 3 + (row)) * FSC + (col)]
#define MF(row, col)       stg[(12 + (row)) * FSC + (col)]

// ---- K1: stats1 via moment matrix. ws[0..3]=S=sum(pn), ws[4..13]=M=sum(pn pn^T)
// packed (00,01,02,03,11,12,13,22,23,33), ws[14]=masked count, ws[15]=center count.
__global__ __launch_bounds__(256, 4) void k_stats1(
    const float* __restrict__ x, const float* __restrict__ mask,
    float* __restrict__ ws) {
  __shared__ float stg[15 * SCOLS];
  __shared__ float red[4][16];
  int tile = swz_tile(blockIdx.x);
  int p0 = tile * 256;
  int b = p0 >> 16, s0 = p0 & (HW_ - 1);
  int h = s0 >> 10, w0 = s0 & (W_ - 1);
  const float* xb = x + (size_t)b * C_ * HW_;
  const float* mb = mask + (size_t)b * HW_;
  stage_rows<256, SCOLS>(xb, mb, h, w0, stg, threadIdx.x);
  __syncthreads();

  int pix = threadIdx.x;
  float xc0 = XSTG(0, 1, 1 + pix), xc1 = XSTG(1, 1, 1 + pix);
  float xc2 = XSTG(2, 1, 1 + pix), xc3 = XSTG(3, 1, 1 + pix);

  float a[16];
#pragma unroll
  for (int i = 0; i < 16; i++) a[i] = 0.f;
  a[15] = (MSTG(1, 1 + pix) > 0.f) ? 1.f : 0.f;

#pragma unroll
  for (int k = 0; k < 9; k++) {
    int row = k / 3, col = 1 + pix + (k % 3 - 1);
    float mval = MSTG(row, col);
    if (mval > 0.f) {
      float pn0 = XSTG(0, row, col) - xc0;
      float pn1 = XSTG(1, row, col) - xc1;
      float pn2 = XSTG(2, row, col) - xc2;
      float pn3 = XSTG(3, row, col) - xc3;
      a[14] += 1.f;
      a[0] += pn0; a[1] += pn1; a[2] += pn2; a[3] += pn3;
      a[4] += pn0 * pn0; a[5] += pn0 * pn1; a[6] += pn0 * pn2; a[7] += pn0 * pn3;
      a[8] += pn1 * pn1; a[9] += pn1 * pn2; a[10] += pn1 * pn3;
      a[11] += pn2 * pn2; a[12] += pn2 * pn3; a[13] += pn3 * pn3;
    }
  }
  int lane = threadIdx.x & 63, wave = threadIdx.x >> 6;
#pragma unroll
  for (int i = 0; i < 16; i++) {
    float rv = wred(a[i]);
    if (lane == 0) red[wave][i] = rv;
  }
  __syncthreads();
  if (threadIdx.x < 16)
    atomicAdd(&ws[threadIdx.x],
              red[0][threadIdx.x] + red[1][threadIdx.x] + red[2][threadIdx.x] + red[3][threadIdx.x]);
}

// ---- K2: stats2, 2 threads/pixel (grid 1024); gbn1 scale from S/M ----
__global__ __launch_bounds__(256, 4) void k_stats2(
    const float* __restrict__ x, const float* __restrict__ mask,
    const float* __restrict__ g1, const float* __restrict__ gbn1_g,
    const float* __restrict__ gbn1_b, const float* __restrict__ g2,
    float* __restrict__ ws) {
  __shared__ float stg[15 * SCOLS];
  __shared__ float red[4][16];
  __shared__ float sc[8], sh[8];
  if (threadIdx.x < 8) {
    int o = threadIdx.x;
    float a0 = g1[o * 4], a1 = g1[o * 4 + 1], a2 = g1[o * 4 + 2], a3 = g1[o * 4 + 3];
    float n = fmaxf(ws[14], 1.f);
    float mean = (a0 * ws[0] + a1 * ws[1] + a2 * ws[2] + a3 * ws[3]) / n;
    float q = a0 * a0 * ws[4] + a1 * a1 * ws[8] + a2 * a2 * ws[11] + a3 * a3 * ws[13]
            + 2.f * (a0 * a1 * ws[5] + a0 * a2 * ws[6] + a0 * a3 * ws[7]
                   + a1 * a2 * ws[9] + a1 * a3 * ws[10] + a2 * a3 * ws[12]);
    float var = q / n - mean * mean;
    float s_ = gbn1_g[o] * rsqrtf(var + EPS);
    sc[o] = s_; sh[o] = gbn1_b[o] - mean * s_;
  }
  int half = blockIdx.x >> 9;
  int tile = swz_tile(blockIdx.x & 511);
  int p0 = tile * 256;
  int b = p0 >> 16, s0 = p0 & (HW_ - 1);
  int h = s0 >> 10, w0 = s0 & (W_ - 1);
  const float* xb = x + (size_t)b * C_ * HW_;
  const float* mb = mask + (size_t)b * HW_;
  stage_rows<256, SCOLS>(xb, mb, h, w0, stg, threadIdx.x);
  __syncthreads();

  int pix = threadIdx.x;
  float xc0 = XSTG(0, 1, 1 + pix), xc1 = XSTG(1, 1, 1 + pix);
  float xc2 = XSTG(2, 1, 1 + pix), xc3 = XSTG(3, 1, 1 + pix);

  float acc2[16];
#pragma unroll
  for (int i = 0; i < 16; i++) acc2[i] = 0.f;

  int kb = half ? 5 : 0, ke = half ? 9 : 5;
#pragma unroll
  for (int k = 0; k < 9; k++) {
    if (k < kb || k >= ke) continue;
    int row = k / 3, col = 1 + pix + (k % 3 - 1);
    float mval = MSTG(row, col);
    if (mval > 0.f) {
      float pn0 = XSTG(0, row, col) - xc0;
      float pn1 = XSTG(1, row, col) - xc1;
      float pn2 = XSTG(2, row, col) - xc2;
      float pn3 = XSTG(3, row, col) - xc3;
      float gb[8];
#pragma unroll
      for (int o = 0; o < 8; o++) {
        float tg = pn0 * g1[o * 4] + pn1 * g1[o * 4 + 1] + pn2 * g1[o * 4 + 2] + pn3 * g1[o * 4 + 3];
        gb[o] = fmaxf(sc[o] * tg + sh[o], 0.f);
      }
#pragma unroll
      for (int j = 0; j < 8; j++) {
        float t2 = 0.f;
#pragma unroll
        for (int o = 0; o < 8; o++) t2 += gb[o] * g2[j * 8 + o];
        acc2[j] += t2; acc2[8 + j] += t2 * t2;
      }
    }
  }
  int lane = threadIdx.x & 63, wave = threadIdx.x >> 6;
#pragma unroll
  for (int i = 0; i < 16; i++) {
    float rv = wred(acc2[i]);
    if (lane == 0) red[wave][i] = rv;
  }
  __syncthreads();
  if (threadIdx.x < 16)
    atomicAdd(&ws[40 + threadIdx.x],
              red[0][threadIdx.x] + red[1][threadIdx.x] + red[2][threadIdx.x] + red[3][threadIdx.x]);
}

// --------- K3: fused kernel, 512 thr / 128 pixels (4 thr/pixel) -------------
// quarters own neighbors {0,1,2},{3,4},{5,6},{7,8}; fagg 16 channels each.
// LDS ~39.9KB -> 4 blocks/CU; launch_bounds(512,4) (VGPR cap 128, NO spill --
// (512,6) in R10 forced ~85-VGPR cap and spilled: FETCH/WRITE tripled).
__global__ __launch_bounds__(512, 4) void k_fused(
    const float* __restrict__ x, const float* __restrict__ mask,
    const float* __restrict__ w1, const float* __restrict__ bn1_g,
    const float* __restrict__ bn1_b, const float* __restrict__ w2,
    const float* __restrict__ b2, const float* __restrict__ g1,
    const float* __restrict__ gbn1_g, const float* __restrict__ gbn1_b,
    const float* __restrict__ g2, const float* __restrict__ gbn2_g,
    const float* __restrict__ gbn2_b, const float* __restrict__ w_agg,
    const float* __restrict__ ws, float* __restrict__ out_pre,
    float* __restrict__ wsum) {
  __shared__ uint4 vecA[17][128];   // 34.8 KB : staging overlay, then bf16 chunks
  __shared__ float evb[9][128];     // 4.5 KB  : softmax logit exchange
  __shared__ float sA[8], hA[8], sG1[8], hG1[8], sG2[8], hG2[8];
  float* stg = (float*)&vecA[0][0]; // 7.8 KB < chunks-8+ offset (16 KB): phase-3 safe

  if (threadIdx.x < 16) {
    int o = threadIdx.x & 7;
    const float* wv = (threadIdx.x < 8) ? w1 : g1;
    float a0 = wv[o * 4], a1 = wv[o * 4 + 1], a2 = wv[o * 4 + 2], a3 = wv[o * 4 + 3];
    float n = fmaxf(ws[14], 1.f);
    float mean = (a0 * ws[0] + a1 * ws[1] + a2 * ws[2] + a3 * ws[3]) / n;
    float q = a0 * a0 * ws[4] + a1 * a1 * ws[8] + a2 * a2 * ws[11] + a3 * a3 * ws[13]
            + 2.f * (a0 * a1 * ws[5] + a0 * a2 * ws[6] + a0 * a3 * ws[7]
                   + a1 * a2 * ws[9] + a1 * a3 * ws[10] + a2 * a3 * ws[12]);
    float var = q / n - mean * mean;
    float gma = (threadIdx.x < 8) ? bn1_g[o] : gbn1_g[o];
    float bta = (threadIdx.x < 8) ? bn1_b[o] : gbn1_b[o];
    float s_ = gma * rsqrtf(var + EPS);
    float sft = bta - mean * s_;
    if (threadIdx.x < 8) { sA[o] = s_;  hA[o] = sft; }
    else                 { sG1[o] = s_; hG1[o] = sft; }
  } else if (threadIdx.x < 24) {
    int o = threadIdx.x & 7;
    float n = fmaxf(ws[14], 1.f);
    float mean = ws[40 + o] / n, var = ws[48 + o] / n - mean * mean;
    float s_ = gbn2_g[o] * rsqrtf(var + EPS);
    sG2[o] = s_; hG2[o] = gbn2_b[o] - mean * s_;
  }

  int tid = threadIdx.x;
  int quarter = tid >> 7;   // wave-uniform (2 waves per quarter)
  int pix = tid & 127;
  int tile = (blockIdx.x & 7) * 128 + (blockIdx.x >> 3);  // XCD-contiguous, 1024 tiles
  int p0 = tile * 128;
  int b = p0 >> 16, s0 = p0 & (HW_ - 1);
  int h = s0 >> 10, w0 = s0 & (W_ - 1);
  const float* xb = x + (size_t)b * C_ * HW_;
  const float* mb = mask + (size_t)b * HW_;
  stage_rows<512, FSC>(xb, mb, h, w0, stg, tid);
  __syncthreads();

  float xc0 = XF(0, 1, 1 + pix), xc1 = XF(1, 1, 1 + pix);
  float xc2 = XF(2, 1, 1 + pix), xc3 = XF(3, 1, 1 + pix);
  float b2v = b2[0];

  // quarter k-ranges: q0 [0,3), q1 [3,5), q2 [5,7), q3 [7,9)
  int kb = (quarter == 0) ? 0 : (2 * quarter + 1);
  int ke = 2 * quarter + 3;

  // ---- phase 1: softmax logits for my neighbors; cache pn in registers ----
  float pnc[3][4];
  unsigned mbits = 0u;
#pragma unroll
  for (int k = 0; k < 9; k++) {
    if (k < kb || k >= ke) continue;
    int j = k - kb;
    int row = k / 3, col = 1 + pix + (k % 3 - 1);
    float mval = MF(row, col);
    float wp = 0.f;
    pnc[j][0] = 0.f; pnc[j][1] = 0.f; pnc[j][2] = 0.f; pnc[j][3] = 0.f;
    if (mval > 0.f) {
      mbits |= (1u << k);
      pnc[j][0] = XF(0, row, col) - xc0;
      pnc[j][1] = XF(1, row, col) - xc1;
      pnc[j][2] = XF(2, row, col) - xc2;
      pnc[j][3] = XF(3, row, col) - xc3;
      float accw = 0.f;
#pragma unroll
      for (int o = 0; o < 8; o++) {
        float ta = pnc[j][0] * w1[o * 4] + pnc[j][1] * w1[o * 4 + 1] +
                   pnc[j][2] * w1[o * 4 + 2] + pnc[j][3] * w1[o * 4 + 3];
        accw += fmaxf(sA[o] * ta + hA[o], 0.f) * w2[o];
      }
      wp = accw + b2v;
    }
    evb[k][pix] = wp;
  }
  __syncthreads();   // evb ready; staging reads done before phase-4 overwrite

  // ---- phase 2: all quarters compute identical softmax weights ----
  float ev[9];
  float mx = -1e30f;
#pragma unroll
  for (int k = 0; k < 9; k++) { ev[k] = evb[k][pix]; mx = fmaxf(mx, ev[k]); }
  float den = 0.f;
#pragma unroll
  for (int k = 0; k < 9; k++) { ev[k] = __expf(ev[k] - mx); den += ev[k]; }
  float inv = 1.f / den;

  // ---- phase 3: g-vec for my neighbors (register pn, zero loads) ----
#pragma unroll
  for (int k = 0; k < 9; k++) {
    if (k < kb || k >= ke) continue;
    int j = k - kb;
    uint4 pk; pk.x = pk.y = pk.z = pk.w = 0u;
    if ((mbits >> k) & 1u) {
      float wt = ev[k] * inv;
      float gb[8];
#pragma unroll
      for (int o = 0; o < 8; o++) {
        float tg = pnc[j][0] * g1[o * 4] + pnc[j][1] * g1[o * 4 + 1] +
                   pnc[j][2] * g1[o * 4 + 2] + pnc[j][3] * g1[o * 4 + 3];
        gb[o] = fmaxf(sG1[o] * tg + hG1[o], 0.f);
      }
      float gv[8];
#pragma unroll
      for (int j2 = 0; j2 < 8; j2++) {
        float t2 = 0.f;
#pragma unroll
        for (int o = 0; o < 8; o++) t2 += gb[o] * g2[j2 * 8 + o];
        float gg = fmaxf(sG2[j2] * t2 + hG2[j2], 0.f);
        gv[j2] = wt * gg;
      }
      pk.x = pack2(gv[0], gv[1]); pk.y = pack2(gv[2], gv[3]);
      pk.z = pack2(gv[4], gv[5]); pk.w = pack2(gv[6], gv[7]);
    }
    vecA[8 + k][pix] = pk;
  }

  // ---- phase 4: fagg over my 16 channels, all 9 neighbors (coalesced) ----
  float facc[16];
#pragma unroll
  for (int c = 0; c < 16; c++) facc[c] = 0.f;
#pragma unroll
  for (int k = 0; k < 9; k++) {
    int di = k / 3 - 1, dj = k % 3 - 1;
    int hh = h + di, ww = w0 + pix + dj;
    bool inb = ((unsigned)hh < (unsigned)H_) && ((unsigned)ww < (unsigned)W_);
    if (inb) {
      int ns = (hh << 10) + ww;
      float wt = ev[k] * inv;
      const float* xf = xb + (size_t)(4 + quarter * 16) * HW_ + ns;
#pragma unroll
      for (int c = 0; c < 16; c++) facc[c] += wt * xf[(size_t)c * HW_];
    }
  }
#pragma unroll
  for (int c0 = 0; c0 < 16; c0 += 8) {
    uint4 pk;
    pk.x = pack2(facc[c0], facc[c0 + 1]);     pk.y = pack2(facc[c0 + 2], facc[c0 + 3]);
    pk.z = pack2(facc[c0 + 4], facc[c0 + 5]); pk.w = pack2(facc[c0 + 6], facc[c0 + 7]);
    vecA[quarter * 2 + (c0 >> 3)][pix] = pk;
  }
  __syncthreads();

  // ---- GEMM: D[pixel 128][chan 64] = vecA @ w_agg^T, 8 waves (4 m-pair x 2 n)
  int lane = tid & 63, wave = tid >> 6;
  int q = lane >> 4, r = lane & 15;
  int wr = wave >> 1, wc = wave & 1;

  short8 Bf[2][5];
#pragma unroll
  for (int nt = 0; nt < 2; nt++) {
    int n = wc * 32 + nt * 16 + r;
#pragma unroll
    for (int ks = 0; ks < 5; ks++) {
      int k0 = ks * 32 + q * 8;
      uint4 pk; pk.x = pk.y = pk.z = pk.w = 0u;
      if (k0 < 136) {
        float4 f0 = *reinterpret_cast<const float4*>(w_agg + n * 136 + k0);
        float4 f1 = *reinterpret_cast<const float4*>(w_agg + n * 136 + k0 + 4);
        pk.x = pack2(f0.x, f0.y); pk.y = pack2(f0.z, f0.w);
        pk.z = pack2(f1.x, f1.y); pk.w = pack2(f1.z, f1.w);
      }
      Bf[nt][ks] = *reinterpret_cast<short8*>(&pk);
    }
  }

  floatx4 acc[2][2];
#pragma unroll
  for (int m = 0; m < 2; m++)
#pragma unroll
    for (int nt = 0; nt < 2; nt++) acc[m][nt] = (floatx4){0.f, 0.f, 0.f, 0.f};

#pragma unroll
  for (int m = 0; m < 2; m++) {
    int pixm = (wr * 2 + m) * 16 + r;
    short8 Af[5];
#pragma unroll
    for (int ks = 0; ks < 5; ks++) {
      int chunk = ks * 4 + q;
      if (chunk < 17)
        Af[ks] = *reinterpret_cast<const short8*>(&vecA[chunk][pixm]);
      else
        Af[ks] = (short8){0, 0, 0, 0, 0, 0, 0, 0};
    }
#pragma unroll
    for (int nt = 0; nt < 2; nt++)
#pragma unroll
      for (int ks = 0; ks < 5; ks++)
        acc[m][nt] = __builtin_amdgcn_mfma_f32_16x16x32_bf16(Af[ks], Bf[nt][ks], acc[m][nt], 0, 0, 0);
  }

  // ---- store (f32, full-line coalesced) + masked abn partial sums ----
  float aS[2] = {0.f, 0.f}, aQ[2] = {0.f, 0.f};
#pragma unroll
  for (int m = 0; m < 2; m++) {
    int mt = wr * 2 + m;
    int srow = s0 + mt * 16 + q * 4;
    float4 mv = *reinterpret_cast<const float4*>(mb + srow);
    float m0 = (mv.x > 0.f) ? 1.f : 0.f, m1 = (mv.y > 0.f) ? 1.f : 0.f;
    float m2 = (mv.z > 0.f) ? 1.f : 0.f, m3 = (mv.w > 0.f) ? 1.f : 0.f;
#pragma unroll
    for (int nt = 0; nt < 2; nt++) {
      int ch = wc * 32 + nt * 16 + r;
      float4 ov;
      ov.x = acc[m][nt][0]; ov.y = acc[m][nt][1];
      ov.z = acc[m][nt][2]; ov.w = acc[m][nt][3];
      aS[nt] += ov.x * m0 + ov.y * m1 + ov.z * m2 + ov.w * m3;
      aQ[nt] += ov.x * ov.x * m0 + ov.y * ov.y * m1 + ov.z * ov.z * m2 + ov.w * ov.w * m3;
      *reinterpret_cast<float4*>(out_pre + ((size_t)(b * 64 + ch)) * HW_ + srow) = ov;
    }
  }

  __syncthreads();  // all vecA ds_reads done; reuse LDS for reduction
  float* rS = (float*)&vecA[0][0];   // [8 waves][2 nt][16 r]
  float* rQ = rS + 256;
#pragma unroll
  for (int nt = 0; nt < 2; nt++) {
    float v1 = aS[nt], v2 = aQ[nt];
    v1 += __shfl_xor(v1, 16); v1 += __shfl_xor(v1, 32);
    v2 += __shfl_xor(v2, 16); v2 += __shfl_xor(v2, 32);
    if (lane < 16) { rS[wave * 32 + nt * 16 + lane] = v1; rQ[wave * 32 + nt * 16 + lane] = v2; }
  }
  __syncthreads();
  if (tid < 64) {
    int c = tid;
    int wc_ = c >> 5, nt_ = (c >> 4) & 1, r_ = c & 15;
    float s1 = 0.f, s2 = 0.f;
#pragma unroll
    for (int wr_ = 0; wr_ < 4; wr_++) {
      int idx = (wr_ * 2 + wc_) * 32 + nt_ * 16 + r_;
      s1 += rS[idx]; s2 += rQ[idx];
    }
    atomicAdd(&wsum[64 + c], s1);
    atomicAdd(&wsum[128 + c], s2);
  }
}

// ---------------- K4: abn apply + relu + center-mask zero (f32 in) ----------
__global__ __launch_bounds__(256) void k_final(
    const float* __restrict__ out_pre, const float* __restrict__ mask,
    const float* __restrict__ abn_g, const float* __restrict__ abn_b,
    const float* __restrict__ ws, float* __restrict__ out) {
  __shared__ float sc[64], sh[64];
  if (threadIdx.x < 64) {
    int c = threadIdx.x;
    float n0 = fmaxf(ws[15], 1.f);
    float mean = ws[64 + c] / n0;
    float var = ws[128 + c] / n0 - mean * mean;
    float s_ = abn_g[c] * rsqrtf(var + EPS);
    sc[c] = s_; sh[c] = abn_b[c] - mean * s_;
  }
  __syncthreads();
  int i4 = (blockIdx.x * 256 + threadIdx.x) * 4;
  if (i4 >= B_ * 64 * HW_) return;
  int c = (i4 >> 16) & 63;
  int b = i4 >> 22;
  int s = i4 & (HW_ - 1);
  float4 v = *reinterpret_cast<const float4*>(out_pre + i4);
  float4 m = *reinterpret_cast<const float4*>(mask + (size_t)b * HW_ + s);
  float4 o;
  o.x = (m.x > 0.f) ? fmaxf(v.x * sc[c] + sh[c], 0.f) : 0.f;
  o.y = (m.y > 0.f) ? fmaxf(v.y * sc[c] + sh[c], 0.f) : 0.f;
  o.z = (m.z > 0.f) ? fmaxf(v.z * sc[c] + sh[c], 0.f) : 0.f;
  o.w = (m.w > 0.f) ? fmaxf(v.w * sc[c] + sh[c], 0.f) : 0.f;
  *reinterpret_cast<float4*>(out + i4) = o;
}

extern "C" void kernel_launch(void* const* d_in, const int* in_sizes, int n_in,
                              void* d_out, int out_size, void* d_ws, size_t ws_size,
                              hipStream_t stream) {
  const float* x      = (const float*)d_in[0];
  const float* mask   = (const float*)d_in[1];
  const float* w1     = (const float*)d_in[2];
  const float* bn1_g  = (const float*)d_in[3];
  const float* bn1_b  = (const float*)d_in[4];
  const float* w2     = (const float*)d_in[5];
  const float* b2     = (const float*)d_in[6];
  const float* g1     = (const float*)d_in[7];
  const float* gbn1_g = (const float*)d_in[8];
  const float* gbn1_b = (const float*)d_in[9];
  const float* g2     = (const float*)d_in[10];
  const float* gbn2_g = (const float*)d_in[11];
  const float* gbn2_b = (const float*)d_in[12];
  const float* w_agg  = (const float*)d_in[13];
  const float* abn_g  = (const float*)d_in[14];
  const float* abn_b  = (const float*)d_in[15];
  float* out = (float*)d_out;

  size_t need = 1024 + (size_t)NPIX * 64 * 4;
  if (ws_size < need) return;

  float* wsf = (float*)d_ws;
  float* out_pre = (float*)((char*)d_ws + 1024);

  hipMemsetAsync(d_ws, 0, 1024, stream);
  k_stats1<<<512, 256, 0, stream>>>(x, mask, wsf);
  k_stats2<<<1024, 256, 0, stream>>>(x, mask, g1, gbn1_g, gbn1_b, g2, wsf);
  k_fused<<<1024, 512, 0, stream>>>(x, mask, w1, bn1_g, bn1_b, w2, b2, g1,
                                    gbn1_g, gbn1_b, g2, gbn2_g, gbn2_b, w_agg,
                                    wsf, out_pre, wsf);
  k_final<<<8192, 256, 0, stream>>>(out_pre, mask, abn_g, abn_b, wsf, out);
}

// Round 12
// 185.066 us; speedup vs baseline: 1.2973x; 1.1059x over previous
//
#include <hip/hip_runtime.h>

#define HW_ 65536
#define W_ 1024
#define H_ 64
#define B_ 2
#define C_ 68
#define NPIX 131072
#define EPS 1e-5f
#define SCOLS 258            // 256-pixel tiles + halo

typedef __attribute__((ext_vector_type(8))) short short8;
typedef __attribute__((ext_vector_type(4))) float floatx4;

__device__ __forceinline__ unsigned short f2bf(float f) {
  unsigned u = __float_as_uint(f);
  u += 0x7fffu + ((u >> 16) & 1u);
  return (unsigned short)(u >> 16);
}
__device__ __forceinline__ unsigned pack2(float a, float b) {
  return (unsigned)f2bf(a) | ((unsigned)f2bf(b) << 16);
}
__device__ __forceinline__ float wred(float v) {
  v += __shfl_xor(v, 1);  v += __shfl_xor(v, 2);  v += __shfl_xor(v, 4);
  v += __shfl_xor(v, 8);  v += __shfl_xor(v, 16); v += __shfl_xor(v, 32);
  return v;
}
__device__ __forceinline__ int swz_tile(int bid) {
  // XCD-contiguous (512 tiles): XCD j (= bid%8) owns tiles [j*64, j*64+64)
  return (bid & 7) * 64 + (bid >> 3);
}

// Workspace layout (bytes):
//   [0..1024)      ws[0..255]: ws[0..15] moments (written by k_stats2, identical-
//                  value race), ws[40..55] stats2 atomic sums, ws[64..191] abn
//                  atomic sums. ws[16..255] zeroed by k_stats1 block 0.
//   [1024..33792)  pb[512][16] per-block stats1 partials (plain stores, no init)
//   [40960..58368) w_agg in bf16 (64x136 ushort), converted by k_stats1 blk 0-63
//   [65536.. )     out_pre f32 (NPIX*64)

// Stage 3 rows x SCOLS of x ch0-3 and mask into LDS (15.5 KB). OOB -> 0.
template <int NT>
__device__ __forceinline__ void stage_rows(const float* xb, const float* mb,
                                           int h, int w0, float* stg, int tid) {
  const int tot = 15 * SCOLS;
#pragma unroll 1
  for (int i = tid; i < tot; i += NT) {
    int seg = i / SCOLS, col = i - seg * SCOLS;
    int arr = seg / 3, row = seg - arr * 3;
    int wg = w0 - 1 + col, hg = h + row - 1;
    bool ok = ((unsigned)wg < (unsigned)W_) && ((unsigned)hg < (unsigned)H_);
    float v = 0.f;
    if (ok) v = (arr < 4) ? xb[(size_t)arr * HW_ + (hg << 10) + wg]
                          : mb[(hg << 10) + wg];
    stg[i] = v;
  }
}

#define XSTG(ch, row, col) stg[((ch) * 3 + (row)) * SCOLS + (col)]
#define MSTG(row, col)     stg[(12 + (row)) * SCOLS + (col)]

// ---- K1: stats1 via moment matrix -> per-block partials pb[blk][16].
// pb: 0..3=S=sum(pn), 4..13=M packed (00,01,02,03,11,12,13,22,23,33),
// 14=masked count, 15=center count. Also: block0 zeroes ws[16..255];
// blocks 0..63 convert w_agg row -> bf16 table.
__global__ __launch_bounds__(256, 4) void k_stats1(
    const float* __restrict__ x, const float* __restrict__ mask,
    const float* __restrict__ w_agg, float* __restrict__ ws) {
  __shared__ float stg[15 * SCOLS];
  __shared__ float red[4][16];

  if (blockIdx.x == 0 && threadIdx.x < 240) ws[16 + threadIdx.x] = 0.f;
  if (blockIdx.x < 64 && threadIdx.x < 136) {
    unsigned short* wb = (unsigned short*)((char*)ws + 40960);
    wb[blockIdx.x * 136 + threadIdx.x] = f2bf(w_agg[blockIdx.x * 136 + threadIdx.x]);
  }

  int tile = swz_tile(blockIdx.x);
  int p0 = tile * 256;
  int b = p0 >> 16, s0 = p0 & (HW_ - 1);
  int h = s0 >> 10, w0 = s0 & (W_ - 1);
  const float* xb = x + (size_t)b * C_ * HW_;
  const float* mb = mask + (size_t)b * HW_;
  stage_rows<256>(xb, mb, h, w0, stg, threadIdx.x);
  __syncthreads();

  int pix = threadIdx.x;
  float xc0 = XSTG(0, 1, 1 + pix), xc1 = XSTG(1, 1, 1 + pix);
  float xc2 = XSTG(2, 1, 1 + pix), xc3 = XSTG(3, 1, 1 + pix);

  float a[16];
#pragma unroll
  for (int i = 0; i < 16; i++) a[i] = 0.f;
  a[15] = (MSTG(1, 1 + pix) > 0.f) ? 1.f : 0.f;

#pragma unroll
  for (int k = 0; k < 9; k++) {
    int row = k / 3, col = 1 + pix + (k % 3 - 1);
    float mval = MSTG(row, col);
    if (mval > 0.f) {
      float pn0 = XSTG(0, row, col) - xc0;
      float pn1 = XSTG(1, row, col) - xc1;
      float pn2 = XSTG(2, row, col) - xc2;
      float pn3 = XSTG(3, row, col) - xc3;
      a[14] += 1.f;
      a[0] += pn0; a[1] += pn1; a[2] += pn2; a[3] += pn3;
      a[4] += pn0 * pn0; a[5] += pn0 * pn1; a[6] += pn0 * pn2; a[7] += pn0 * pn3;
      a[8] += pn1 * pn1; a[9] += pn1 * pn2; a[10] += pn1 * pn3;
      a[11] += pn2 * pn2; a[12] += pn2 * pn3; a[13] += pn3 * pn3;
    }
  }
  int lane = threadIdx.x & 63, wave = threadIdx.x >> 6;
#pragma unroll
  for (int i = 0; i < 16; i++) {
    float rv = wred(a[i]);
    if (lane == 0) red[wave][i] = rv;
  }
  __syncthreads();
  if (threadIdx.x < 16)
    ws[256 + blockIdx.x * 16 + threadIdx.x] =
        red[0][threadIdx.x] + red[1][threadIdx.x] + red[2][threadIdx.x] + red[3][threadIdx.x];
}

// ---- K2: stats2, 2 threads/pixel (grid 1024). Prologue: reduce pb[512][16]
// (deterministic -> all blocks write identical ws[0..15]); derive gbn1 scale.
__global__ __launch_bounds__(256, 4) void k_stats2(
    const float* __restrict__ x, const float* __restrict__ mask,
    const float* __restrict__ g1, const float* __restrict__ gbn1_g,
    const float* __restrict__ gbn1_b, const float* __restrict__ g2,
    float* __restrict__ ws) {
  __shared__ float stg[15 * SCOLS];
  __shared__ float red[4][16];
  __shared__ float red2[16][17];
  __shared__ float smom[16];
  __shared__ float sc[8], sh[8];

  {
    int i = threadIdx.x & 15, bg = threadIdx.x >> 4;   // 16 groups x 32 blocks
    const float* pb = ws + 256 + bg * 32 * 16;
    float s = 0.f;
#pragma unroll 8
    for (int bb = 0; bb < 32; bb++) s += pb[bb * 16 + i];
    red2[bg][i] = s;
  }
  __syncthreads();
  if (threadIdx.x < 16) {
    float s = 0.f;
#pragma unroll
    for (int g = 0; g < 16; g++) s += red2[g][threadIdx.x];
    smom[threadIdx.x] = s;
    ws[threadIdx.x] = s;   // identical across blocks -- benign race
  }
  __syncthreads();
  if (threadIdx.x < 8) {
    int o = threadIdx.x;
    float a0 = g1[o * 4], a1 = g1[o * 4 + 1], a2 = g1[o * 4 + 2], a3 = g1[o * 4 + 3];
    float n = fmaxf(smom[14], 1.f);
    float mean = (a0 * smom[0] + a1 * smom[1] + a2 * smom[2] + a3 * smom[3]) / n;
    float q = a0 * a0 * smom[4] + a1 * a1 * smom[8] + a2 * a2 * smom[11] + a3 * a3 * smom[13]
            + 2.f * (a0 * a1 * smom[5] + a0 * a2 * smom[6] + a0 * a3 * smom[7]
                   + a1 * a2 * smom[9] + a1 * a3 * smom[10] + a2 * a3 * smom[12]);
    float var = q / n - mean * mean;
    float s_ = gbn1_g[o] * rsqrtf(var + EPS);
    sc[o] = s_; sh[o] = gbn1_b[o] - mean * s_;
  }

  int half = blockIdx.x >> 9;
  int tile = swz_tile(blockIdx.x & 511);
  int p0 = tile * 256;
  int b = p0 >> 16, s0 = p0 & (HW_ - 1);
  int h = s0 >> 10, w0 = s0 & (W_ - 1);
  const float* xb = x + (size_t)b * C_ * HW_;
  const float* mb = mask + (size_t)b * HW_;
  stage_rows<256>(xb, mb, h, w0, stg, threadIdx.x);
  __syncthreads();

  int pix = threadIdx.x;
  float xc0 = XSTG(0, 1, 1 + pix), xc1 = XSTG(1, 1, 1 + pix);
  float xc2 = XSTG(2, 1, 1 + pix), xc3 = XSTG(3, 1, 1 + pix);

  float acc2[16];
#pragma unroll
  for (int i = 0; i < 16; i++) acc2[i] = 0.f;

  int kb = half ? 5 : 0, ke = half ? 9 : 5;
#pragma unroll
  for (int k = 0; k < 9; k++) {
    if (k < kb || k >= ke) continue;
    int row = k / 3, col = 1 + pix + (k % 3 - 1);
    float mval = MSTG(row, col);
    if (mval > 0.f) {
      float pn0 = XSTG(0, row, col) - xc0;
      float pn1 = XSTG(1, row, col) - xc1;
      float pn2 = XSTG(2, row, col) - xc2;
      float pn3 = XSTG(3, row, col) - xc3;
      float gb[8];
#pragma unroll
      for (int o = 0; o < 8; o++) {
        float tg = pn0 * g1[o * 4] + pn1 * g1[o * 4 + 1] + pn2 * g1[o * 4 + 2] + pn3 * g1[o * 4 + 3];
        gb[o] = fmaxf(sc[o] * tg + sh[o], 0.f);
      }
#pragma unroll
      for (int j = 0; j < 8; j++) {
        float t2 = 0.f;
#pragma unroll
        for (int o = 0; o < 8; o++) t2 += gb[o] * g2[j * 8 + o];
        acc2[j] += t2; acc2[8 + j] += t2 * t2;
      }
    }
  }
  int lane = threadIdx.x & 63, wave = threadIdx.x >> 6;
#pragma unroll
  for (int i = 0; i < 16; i++) {
    float rv = wred(acc2[i]);
    if (lane == 0) red[wave][i] = rv;
  }
  __syncthreads();
  if (threadIdx.x < 16)
    atomicAdd(&ws[40 + threadIdx.x],
              red[0][threadIdx.x] + red[1][threadIdx.x] + red[2][threadIdx.x] + red[3][threadIdx.x]);
}

// --------- K3: fused kernel, 512 thr / 256 pixels (R9-proven) + bf16 Bf table
__global__ __launch_bounds__(512, 4) void k_fused(
    const float* __restrict__ x, const float* __restrict__ mask,
    const float* __restrict__ w1, const float* __restrict__ bn1_g,
    const float* __restrict__ bn1_b, const float* __restrict__ w2,
    const float* __restrict__ b2, const float* __restrict__ g1,
    const float* __restrict__ gbn1_g, const float* __restrict__ gbn1_b,
    const float* __restrict__ g2, const float* __restrict__ gbn2_g,
    const float* __restrict__ gbn2_b, const unsigned short* __restrict__ wb,
    const float* __restrict__ ws, float* __restrict__ out_pre,
    float* __restrict__ wsum) {
  __shared__ uint4 vecA[17][256];   // 69.6 KB : staging overlay, then bf16 chunks
  __shared__ float evb[9][256];     // 9 KB   : softmax logit exchange
  __shared__ float sA[8], hA[8], sG1[8], hG1[8], sG2[8], hG2[8];
  float* stg = (float*)&vecA[0][0];

  if (threadIdx.x < 16) {
    int o = threadIdx.x & 7;
    const float* wv = (threadIdx.x < 8) ? w1 : g1;
    float a0 = wv[o * 4], a1 = wv[o * 4 + 1], a2 = wv[o * 4 + 2], a3 = wv[o * 4 + 3];
    float n = fmaxf(ws[14], 1.f);
    float mean = (a0 * ws[0] + a1 * ws[1] + a2 * ws[2] + a3 * ws[3]) / n;
    float q = a0 * a0 * ws[4] + a1 * a1 * ws[8] + a2 * a2 * ws[11] + a3 * a3 * ws[13]
            + 2.f * (a0 * a1 * ws[5] + a0 * a2 * ws[6] + a0 * a3 * ws[7]
                   + a1 * a2 * ws[9] + a1 * a3 * ws[10] + a2 * a3 * ws[12]);
    float var = q / n - mean * mean;
    float gma = (threadIdx.x < 8) ? bn1_g[o] : gbn1_g[o];
    float bta = (threadIdx.x < 8) ? bn1_b[o] : gbn1_b[o];
    float s_ = gma * rsqrtf(var + EPS);
    float sft = bta - mean * s_;
    if (threadIdx.x < 8) { sA[o] = s_;  hA[o] = sft; }
    else                 { sG1[o] = s_; hG1[o] = sft; }
  } else if (threadIdx.x < 24) {
    int o = threadIdx.x & 7;
    float n = fmaxf(ws[14], 1.f);
    float mean = ws[40 + o] / n, var = ws[48 + o] / n - mean * mean;
    float s_ = gbn2_g[o] * rsqrtf(var + EPS);
    sG2[o] = s_; hG2[o] = gbn2_b[o] - mean * s_;
  }

  int tid = threadIdx.x;
  int half = tid >> 8;      // 0: k 0..4, 1: k 5..8  (wave-uniform)
  int pix = tid & 255;
  int tile = swz_tile(blockIdx.x);
  int p0 = tile * 256;
  int b = p0 >> 16, s0 = p0 & (HW_ - 1);
  int h = s0 >> 10, w0 = s0 & (W_ - 1);
  const float* xb = x + (size_t)b * C_ * HW_;
  const float* mb = mask + (size_t)b * HW_;
  stage_rows<512>(xb, mb, h, w0, stg, tid);
  __syncthreads();

  float xc0 = XSTG(0, 1, 1 + pix), xc1 = XSTG(1, 1, 1 + pix);
  float xc2 = XSTG(2, 1, 1 + pix), xc3 = XSTG(3, 1, 1 + pix);
  float b2v = b2[0];

  // ---- phase 1: softmax logits for my neighbors; cache pn in registers ----
  float pnc[5][4];
  unsigned mbits = 0u;
  int kb = half ? 5 : 0, ke = half ? 9 : 5;
#pragma unroll
  for (int k = 0; k < 9; k++) {
    if (k < kb || k >= ke) continue;
    int j = k - kb;
    int row = k / 3, col = 1 + pix + (k % 3 - 1);
    float mval = MSTG(row, col);
    float wp = 0.f;
    pnc[j][0] = 0.f; pnc[j][1] = 0.f; pnc[j][2] = 0.f; pnc[j][3] = 0.f;
    if (mval > 0.f) {
      mbits |= (1u << k);
      pnc[j][0] = XSTG(0, row, col) - xc0;
      pnc[j][1] = XSTG(1, row, col) - xc1;
      pnc[j][2] = XSTG(2, row, col) - xc2;
      pnc[j][3] = XSTG(3, row, col) - xc3;
      float accw = 0.f;
#pragma unroll
      for (int o = 0; o < 8; o++) {
        float ta = pnc[j][0] * w1[o * 4] + pnc[j][1] * w1[o * 4 + 1] +
                   pnc[j][2] * w1[o * 4 + 2] + pnc[j][3] * w1[o * 4 + 3];
        accw += fmaxf(sA[o] * ta + hA[o], 0.f) * w2[o];
      }
      wp = accw + b2v;
    }
    evb[k][pix] = wp;
  }
  __syncthreads();   // evb ready; staging reads done before phase-4 overwrite

  // ---- phase 2: both halves compute identical softmax weights ----
  float ev[9];
  float mx = -1e30f;
#pragma unroll
  for (int k = 0; k < 9; k++) { ev[k] = evb[k][pix]; mx = fmaxf(mx, ev[k]); }
  float den = 0.f;
#pragma unroll
  for (int k = 0; k < 9; k++) { ev[k] = __expf(ev[k] - mx); den += ev[k]; }
  float inv = 1.f / den;

  // ---- phase 3: g-vec for my neighbors (register pn, zero loads) ----
#pragma unroll
  for (int k = 0; k < 9; k++) {
    if (k < kb || k >= ke) continue;
    int j = k - kb;
    uint4 pk; pk.x = pk.y = pk.z = pk.w = 0u;
    if ((mbits >> k) & 1u) {
      float wt = ev[k] * inv;
      float gb[8];
#pragma unroll
      for (int o = 0; o < 8; o++) {
        float tg = pnc[j][0] * g1[o * 4] + pnc[j][1] * g1[o * 4 + 1] +
                   pnc[j][2] * g1[o * 4 + 2] + pnc[j][3] * g1[o * 4 + 3];
        gb[o] = fmaxf(sG1[o] * tg + hG1[o], 0.f);
      }
      float gv[8];
#pragma unroll
      for (int j2 = 0; j2 < 8; j2++) {
        float t2 = 0.f;
#pragma unroll
        for (int o = 0; o < 8; o++) t2 += gb[o] * g2[j2 * 8 + o];
        float gg = fmaxf(sG2[j2] * t2 + hG2[j2], 0.f);
        gv[j2] = wt * gg;
      }
      pk.x = pack2(gv[0], gv[1]); pk.y = pack2(gv[2], gv[3]);
      pk.z = pack2(gv[4], gv[5]); pk.w = pack2(gv[6], gv[7]);
    }
    vecA[8 + k][pix] = pk;
  }

  // ---- phase 4: fagg over my 32 channels, all 9 neighbors (coalesced) ----
  float facc[32];
#pragma unroll
  for (int c = 0; c < 32; c++) facc[c] = 0.f;
#pragma unroll
  for (int k = 0; k < 9; k++) {
    int di = k / 3 - 1, dj = k % 3 - 1;
    int hh = h + di, ww = w0 + pix + dj;
    bool inb = ((unsigned)hh < (unsigned)H_) && ((unsigned)ww < (unsigned)W_);
    if (inb) {
      int ns = (hh << 10) + ww;
      float wt = ev[k] * inv;
      const float* xf = xb + (size_t)(4 + half * 32) * HW_ + ns;
#pragma unroll
      for (int c = 0; c < 32; c++) facc[c] += wt * xf[(size_t)c * HW_];
    }
  }
#pragma unroll
  for (int c0 = 0; c0 < 32; c0 += 8) {
    uint4 pk;
    pk.x = pack2(facc[c0], facc[c0 + 1]);     pk.y = pack2(facc[c0 + 2], facc[c0 + 3]);
    pk.z = pack2(facc[c0 + 4], facc[c0 + 5]); pk.w = pack2(facc[c0 + 6], facc[c0 + 7]);
    vecA[(half * 32 + c0) >> 3][pix] = pk;
  }
  __syncthreads();

  // ---- GEMM: D[pixel 256][chan 64] = vecA @ w_agg^T, 8 waves (4 m x 2 n) ----
  int lane = tid & 63, wave = tid >> 6;
  int q = lane >> 4, r = lane & 15;
  int wr = wave >> 1, wc = wave & 1;

  short8 Bf[2][5];
#pragma unroll
  for (int nt = 0; nt < 2; nt++) {
    int n = wc * 32 + nt * 16 + r;
#pragma unroll
    for (int ks = 0; ks < 5; ks++) {
      int k0 = ks * 32 + q * 8;
      uint4 pk; pk.x = pk.y = pk.z = pk.w = 0u;
      if (k0 < 136)
        pk = *reinterpret_cast<const uint4*>(wb + n * 136 + k0);
      Bf[nt][ks] = *reinterpret_cast<short8*>(&pk);
    }
  }

  floatx4 acc[4][2];
#pragma unroll
  for (int m = 0; m < 4; m++)
#pragma unroll
    for (int nt = 0; nt < 2; nt++) acc[m][nt] = (floatx4){0.f, 0.f, 0.f, 0.f};

#pragma unroll
  for (int m = 0; m < 4; m++) {
    int pixm = (wr * 4 + m) * 16 + r;
    short8 Af[5];
#pragma unroll
    for (int ks = 0; ks < 5; ks++) {
      int chunk = ks * 4 + q;
      if (chunk < 17)
        Af[ks] = *reinterpret_cast<const short8*>(&vecA[chunk][pixm]);
      else
        Af[ks] = (short8){0, 0, 0, 0, 0, 0, 0, 0};
    }
#pragma unroll
    for (int nt = 0; nt < 2; nt++)
#pragma unroll
      for (int ks = 0; ks < 5; ks++)
        acc[m][nt] = __builtin_amdgcn_mfma_f32_16x16x32_bf16(Af[ks], Bf[nt][ks], acc[m][nt], 0, 0, 0);
  }

  // ---- store (f32, full-line coalesced) + masked abn partial sums ----
  float aS[2] = {0.f, 0.f}, aQ[2] = {0.f, 0.f};
#pragma unroll
  for (int m = 0; m < 4; m++) {
    int mt = wr * 4 + m;
    int srow = s0 + mt * 16 + q * 4;
    float4 mv = *reinterpret_cast<const float4*>(mb + srow);
    float m0 = (mv.x > 0.f) ? 1.f : 0.f, m1 = (mv.y > 0.f) ? 1.f : 0.f;
    float m2 = (mv.z > 0.f) ? 1.f : 0.f, m3 = (mv.w > 0.f) ? 1.f : 0.f;
#pragma unroll
    for (int nt = 0; nt < 2; nt++) {
      int ch = wc * 32 + nt * 16 + r;
      float4 ov;
      ov.x = acc[m][nt][0]; ov.y = acc[m][nt][1];
      ov.z = acc[m][nt][2]; ov.w = acc[m][nt][3];
      aS[nt] += ov.x * m0 + ov.y * m1 + ov.z * m2 + ov.w * m3;
      aQ[nt] += ov.x * ov.x * m0 + ov.y * ov.y * m1 + ov.z * ov.z * m2 + ov.w * ov.w * m3;
      *reinterpret_cast<float4*>(out_pre + ((size_t)(b * 64 + ch)) * HW_ + srow) = ov;
    }
  }

  __syncthreads();  // all vecA ds_reads done; reuse LDS for reduction
  float* rS = (float*)&vecA[0][0];   // [8 waves][2 nt][16 r]
  float* rQ = rS + 256;
#pragma unroll
  for (int nt = 0; nt < 2; nt++) {
    float v1 = aS[nt], v2 = aQ[nt];
    v1 += __shfl_xor(v1, 16); v1 += __shfl_xor(v1, 32);
    v2 += __shfl_xor(v2, 16); v2 += __shfl_xor(v2, 32);
    if (lane < 16) { rS[wave * 32 + nt * 16 + lane] = v1; rQ[wave * 32 + nt * 16 + lane] = v2; }
  }
  __syncthreads();
  if (tid < 64) {
    int c = tid;
    int wc_ = c >> 5, nt_ = (c >> 4) & 1, r_ = c & 15;
    float s1 = 0.f, s2 = 0.f;
#pragma unroll
    for (int wr_ = 0; wr_ < 4; wr_++) {
      int idx = (wr_ * 2 + wc_) * 32 + nt_ * 16 + r_;
      s1 += rS[idx]; s2 += rQ[idx];
    }
    atomicAdd(&wsum[64 + c], s1);
    atomicAdd(&wsum[128 + c], s2);
  }
}

// ---------------- K4: abn apply + relu + center-mask zero (f32 in) ----------
__global__ __launch_bounds__(256) void k_final(
    const float* __restrict__ out_pre, const float* __restrict__ mask,
    const float* __restrict__ abn_g, const float* __restrict__ abn_b,
    const float* __restrict__ ws, float* __restrict__ out) {
  __shared__ float sc[64], sh[64];
  if (threadIdx.x < 64) {
    int c = threadIdx.x;
    float n0 = fmaxf(ws[15], 1.f);
    float mean = ws[64 + c] / n0;
    float var = ws[128 + c] / n0 - mean * mean;
    float s_ = abn_g[c] * rsqrtf(var + EPS);
    sc[c] = s_; sh[c] = abn_b[c] - mean * s_;
  }
  __syncthreads();
  int i4 = (blockIdx.x * 256 + threadIdx.x) * 4;
  if (i4 >= B_ * 64 * HW_) return;
  int c = (i4 >> 16) & 63;
  int b = i4 >> 22;
  int s = i4 & (HW_ - 1);
  float4 v = *reinterpret_cast<const float4*>(out_pre + i4);
  float4 m = *reinterpret_cast<const float4*>(mask + (size_t)b * HW_ + s);
  float4 o;
  o.x = (m.x > 0.f) ? fmaxf(v.x * sc[c] + sh[c], 0.f) : 0.f;
  o.y = (m.y > 0.f) ? fmaxf(v.y * sc[c] + sh[c], 0.f) : 0.f;
  o.z = (m.z > 0.f) ? fmaxf(v.z * sc[c] + sh[c], 0.f) : 0.f;
  o.w = (m.w > 0.f) ? fmaxf(v.w * sc[c] + sh[c], 0.f) : 0.f;
  *reinterpret_cast<float4*>(out + i4) = o;
}

extern "C" void kernel_launch(void* const* d_in, const int* in_sizes, int n_in,
                              void* d_out, int out_size, void* d_ws, size_t ws_size,
                              hipStream_t stream) {
  const float* x      = (const float*)d_in[0];
  const float* mask   = (const float*)d_in[1];
  const float* w1     = (const float*)d_in[2];
  const float* bn1_g  = (const float*)d_in[3];
  const float* bn1_b  = (const float*)d_in[4];
  const float* w2     = (const float*)d_in[5];
  const float* b2     = (const float*)d_in[6];
  const float* g1     = (const float*)d_in[7];
  const float* gbn1_g = (const float*)d_in[8];
  const float* gbn1_b = (const float*)d_in[9];
  const float* g2     = (const float*)d_in[10];
  const float* gbn2_g = (const float*)d_in[11];
  const float* gbn2_b = (const float*)d_in[12];
  const float* w_agg  = (const float*)d_in[13];
  const float* abn_g  = (const float*)d_in[14];
  const float* abn_b  = (const float*)d_in[15];
  float* out = (float*)d_out;

  size_t need = 65536 + (size_t)NPIX * 64 * 4;
  if (ws_size < need) return;

  float* wsf = (float*)d_ws;
  const unsigned short* wb = (const unsigned short*)((char*)d_ws + 40960);
  float* out_pre = (float*)((char*)d_ws + 65536);

  // no memset: k_stats1 writes per-block partials (no init needed), its block 0
  // zeroes the atomic targets ws[16..255] used by later kernels.
  k_stats1<<<512, 256, 0, stream>>>(x, mask, w_agg, wsf);
  k_stats2<<<1024, 256, 0, stream>>>(x, mask, g1, gbn1_g, gbn1_b, g2, wsf);
  k_fused<<<512, 512, 0, stream>>>(x, mask, w1, bn1_g, bn1_b, w2, b2, g1,
                                   gbn1_g, gbn1_b, g2, gbn2_g, gbn2_b, wb,
                                   wsf, out_pre, wsf);
  k_final<<<8192, 256, 0, stream>>>(out_pre, mask, abn_g, abn_b, wsf, out);
}